// Round 1
// baseline (1642.575 us; speedup 1.0000x reference)
//
#include <hip/hip_runtime.h>
#include <stdint.h>

// Problem: y[b,s,o] = sum_i x[b,s,i] * (W8[o,i] - zero[o]) * scale[o] + bias[o]
// M = B*S = 8192, N = OUT = 11008, K = IN = 4096.
// Strategy: G = x @ W8^T via bf16 MFMA with split-precision x (hi+lo),
//           y = scale*G - scale*zero*rowsum(x) + bias.

#define M_DIM 8192
#define N_DIM 11008
#define K_DIM 4096

typedef __attribute__((ext_vector_type(8))) __bf16 bf16x8;
typedef __attribute__((ext_vector_type(4))) float f32x4;

__device__ __forceinline__ unsigned short f32_to_bf16_rne(float f) {
  union { float f; uint32_t u; } v; v.f = f;
  uint32_t u = v.u;
  uint32_t r = (u + 0x7fffu + ((u >> 16) & 1u)) >> 16;
  return (unsigned short)r;
}
__device__ __forceinline__ float bf16_to_f32(unsigned short h) {
  union { uint32_t u; float f; } v; v.u = ((uint32_t)h) << 16; return v.f;
}

// ---------------- prep kernels ----------------

// W int32 (int8-valued) -> bf16 bits (exact: |W| <= 128 fits 8-bit mantissa)
__global__ void convert_w_kernel(const int* __restrict__ w,
                                 unsigned short* __restrict__ out, int n4) {
  int idx = blockIdx.x * blockDim.x + threadIdx.x;
  int stride = gridDim.x * blockDim.x;
  for (int i = idx; i < n4; i += stride) {
    int4 v = ((const int4*)w)[i];
    ushort4 o;
    o.x = f32_to_bf16_rne((float)v.x);
    o.y = f32_to_bf16_rne((float)v.y);
    o.z = f32_to_bf16_rne((float)v.z);
    o.w = f32_to_bf16_rne((float)v.w);
    ((ushort4*)out)[i] = o;
  }
}

// x fp32 -> (hi, lo) bf16 split: hi = bf16(x), lo = bf16(x - hi)
__global__ void convert_x_kernel(const float* __restrict__ x,
                                 unsigned short* __restrict__ hi,
                                 unsigned short* __restrict__ lo, int n4) {
  int idx = blockIdx.x * blockDim.x + threadIdx.x;
  int stride = gridDim.x * blockDim.x;
  for (int i = idx; i < n4; i += stride) {
    float4 v = ((const float4*)x)[i];
    ushort4 h, l;
    h.x = f32_to_bf16_rne(v.x); l.x = f32_to_bf16_rne(v.x - bf16_to_f32(h.x));
    h.y = f32_to_bf16_rne(v.y); l.y = f32_to_bf16_rne(v.y - bf16_to_f32(h.y));
    h.z = f32_to_bf16_rne(v.z); l.z = f32_to_bf16_rne(v.z - bf16_to_f32(h.z));
    h.w = f32_to_bf16_rne(v.w); l.w = f32_to_bf16_rne(v.w - bf16_to_f32(h.w));
    ((ushort4*)hi)[i] = h;
    ((ushort4*)lo)[i] = l;
  }
}

// rowsum[m] = sum_k x[m,k]; one wave per row, 4 rows per 256-thread block
__global__ void rowsum_kernel(const float* __restrict__ x, float* __restrict__ rs) {
  const int row = blockIdx.x * 4 + (threadIdx.x >> 6);
  const int lane = threadIdx.x & 63;
  const float4* p = (const float4*)(x + (size_t)row * K_DIM);
  float s = 0.f;
  #pragma unroll 4
  for (int i = lane; i < K_DIM / 4; i += 64) {
    float4 v = p[i];
    s += v.x + v.y + v.z + v.w;
  }
  #pragma unroll
  for (int off = 32; off > 0; off >>= 1) s += __shfl_down(s, off);
  if (lane == 0) rs[row] = s;
}

// ---------------- main GEMM (m97 structure: 128x128 tile, BK=64, 4 waves) ----------------

__global__ __launch_bounds__(256) void qgemm_kernel(
    const unsigned short* __restrict__ Ahi, const unsigned short* __restrict__ Alo,
    const unsigned short* __restrict__ Bw, const float* __restrict__ rowsum,
    const float* __restrict__ scale, const float* __restrict__ zero,
    const float* __restrict__ bias, float* __restrict__ out) {
  __shared__ unsigned short lds[3 * 128 * 64];  // Ahi | Alo | B, each [128][64], 48 KB
  unsigned short* ldsAhi = lds;
  unsigned short* ldsAlo = lds + 128 * 64;
  unsigned short* ldsB   = lds + 2 * 128 * 64;

  const int tid = threadIdx.x;
  const int wave = tid >> 6;
  const int lane = tid & 63;

  // grouped block mapping: 8 m-tiles per group x all n-tiles -> L2/L3 reuse
  const int NUM_N = N_DIM / 128;         // 86
  const int GROUP_M = 8;
  const int per_group = GROUP_M * NUM_N; // 688
  const int bid = blockIdx.x;
  const int group = bid / per_group;
  const int rem = bid % per_group;
  const int bm = group * GROUP_M + (rem % GROUP_M);  // 0..63
  const int bn = rem / GROUP_M;                      // 0..85

  const int wr = wave >> 1;  // 0..1  (64-row half)
  const int wc = wave & 1;   // 0..1  (64-col half)

  f32x4 acc[4][4];
  #pragma unroll
  for (int i = 0; i < 4; ++i)
    #pragma unroll
    for (int j = 0; j < 4; ++j) acc[i][j] = (f32x4){0.f, 0.f, 0.f, 0.f};

  // staging: per issue t, 256 lanes x 16B cover 32 rows x 64 cols (bf16)
  const int srow = tid >> 3;         // 0..31
  const int scol = (tid & 7) * 8;    // k element offset
  const size_t a_base = (size_t)(bm * 128) * K_DIM;
  const size_t b_base = (size_t)(bn * 128) * K_DIM;

  // MFMA fragment addressing (16x16x32): lane -> row (l&15), k-chunk ((l>>4)*8)
  const int fr = lane & 15;
  const int fk = (lane >> 4) * 8;

  for (int ks = 0; ks < K_DIM; ks += 64) {
    #pragma unroll
    for (int t = 0; t < 4; ++t) {
      const int r = t * 32 + srow;
      const unsigned short* ga = Ahi + a_base + (size_t)r * K_DIM + ks + scol;
      const unsigned short* gl = Alo + a_base + (size_t)r * K_DIM + ks + scol;
      const unsigned short* gb = Bw  + b_base + (size_t)r * K_DIM + ks + scol;
      // wave-uniform LDS base; HW adds lane*16
      unsigned short* la = ldsAhi + t * 2048 + wave * 512;
      unsigned short* ll = ldsAlo + t * 2048 + wave * 512;
      unsigned short* lb = ldsB   + t * 2048 + wave * 512;
      __builtin_amdgcn_global_load_lds((const __attribute__((address_space(1))) void*)ga,
                                       (__attribute__((address_space(3))) void*)la, 16, 0, 0);
      __builtin_amdgcn_global_load_lds((const __attribute__((address_space(1))) void*)gl,
                                       (__attribute__((address_space(3))) void*)ll, 16, 0, 0);
      __builtin_amdgcn_global_load_lds((const __attribute__((address_space(1))) void*)gb,
                                       (__attribute__((address_space(3))) void*)lb, 16, 0, 0);
    }
    __syncthreads();

    #pragma unroll
    for (int kk = 0; kk < 64; kk += 32) {
      bf16x8 bfrag[4];
      #pragma unroll
      for (int ni = 0; ni < 4; ++ni) {
        const int row = wc * 64 + ni * 16 + fr;
        bfrag[ni] = *(const bf16x8*)(ldsB + row * 64 + kk + fk);
      }
      #pragma unroll
      for (int mi = 0; mi < 4; ++mi) {
        const int row = wr * 64 + mi * 16 + fr;
        bf16x8 ah = *(const bf16x8*)(ldsAhi + row * 64 + kk + fk);
        bf16x8 al = *(const bf16x8*)(ldsAlo + row * 64 + kk + fk);
        #pragma unroll
        for (int ni = 0; ni < 4; ++ni) {
          acc[mi][ni] = __builtin_amdgcn_mfma_f32_16x16x32_bf16(ah, bfrag[ni], acc[mi][ni], 0, 0, 0);
          acc[mi][ni] = __builtin_amdgcn_mfma_f32_16x16x32_bf16(al, bfrag[ni], acc[mi][ni], 0, 0, 0);
        }
      }
    }
    __syncthreads();
  }

  // epilogue: y = scale*G - scale*zero*rowsum + bias
  const int row0 = bm * 128 + wr * 64;
  const int col0 = bn * 128 + wc * 64;
  float s_[4], sz_[4], b_[4];
  #pragma unroll
  for (int ni = 0; ni < 4; ++ni) {
    const int n = col0 + ni * 16 + fr;
    const float s = scale[n];
    s_[ni] = s;
    sz_[ni] = s * zero[n];
    b_[ni] = bias[n];
  }
  #pragma unroll
  for (int mi = 0; mi < 4; ++mi) {
    #pragma unroll
    for (int j = 0; j < 4; ++j) {
      const int m = row0 + mi * 16 + (lane >> 4) * 4 + j;
      const float rs = rowsum[m];
      float* po = out + (size_t)m * N_DIM + col0;
      #pragma unroll
      for (int ni = 0; ni < 4; ++ni) {
        po[ni * 16 + fr] = s_[ni] * acc[mi][ni][j] - sz_[ni] * rs + b_[ni];
      }
    }
  }
}

// ---------------- fallback (only if workspace too small) ----------------

__global__ void fallback_kernel(const float* __restrict__ x, const int* __restrict__ w,
                                const float* __restrict__ scale, const float* __restrict__ zero,
                                const float* __restrict__ bias, float* __restrict__ out) {
  const int n = blockIdx.x * 16 + (threadIdx.x & 15);
  const int m = blockIdx.y * 16 + (threadIdx.x >> 4);
  const float z = zero[n];
  const float* xr = x + (size_t)m * K_DIM;
  const int* wr = w + (size_t)n * K_DIM;
  float acc = 0.f;
  for (int k = 0; k < K_DIM; ++k) acc += xr[k] * ((float)wr[k] - z);
  out[(size_t)m * N_DIM + n] = scale[n] * acc + bias[n];
}

// ---------------- launch ----------------

extern "C" void kernel_launch(void* const* d_in, const int* in_sizes, int n_in,
                              void* d_out, int out_size, void* d_ws, size_t ws_size,
                              hipStream_t stream) {
  const float* x     = (const float*)d_in[0];
  const int*   w     = (const int*)d_in[1];
  const float* scale = (const float*)d_in[2];
  const float* zero  = (const float*)d_in[3];
  const float* bias  = (const float*)d_in[4];
  float* out = (float*)d_out;

  const size_t n_x = (size_t)M_DIM * K_DIM;  // 33,554,432
  const size_t n_w = (size_t)N_DIM * K_DIM;  // 45,088,768
  const size_t need = n_x * 2 * 2 + n_w * 2 + (size_t)M_DIM * 4;  // ~214 MB

  if (ws_size < need) {
    dim3 g(N_DIM / 16, M_DIM / 16);
    fallback_kernel<<<g, 256, 0, stream>>>(x, w, scale, zero, bias, out);
    return;
  }

  unsigned short* x_hi = (unsigned short*)d_ws;
  unsigned short* x_lo = x_hi + n_x;
  unsigned short* w_bf = x_lo + n_x;
  float* rsum = (float*)(w_bf + n_w);

  convert_w_kernel<<<2048, 256, 0, stream>>>(w, w_bf, (int)(n_w / 4));
  convert_x_kernel<<<2048, 256, 0, stream>>>(x, x_hi, x_lo, (int)(n_x / 4));
  rowsum_kernel<<<M_DIM / 4, 256, 0, stream>>>(x, rsum);

  const int nblocks = (M_DIM / 128) * (N_DIM / 128);  // 64 * 86 = 5504
  qgemm_kernel<<<nblocks, 256, 0, stream>>>(x_hi, x_lo, w_bf, rsum,
                                            scale, zero, bias, out);
}

// Round 2
// 1521.530 us; speedup vs baseline: 1.0796x; 1.0796x over previous
//
#include <hip/hip_runtime.h>
#include <stdint.h>

// Problem: y[b,s,o] = sum_i x[b,s,i] * (W8[o,i] - zero[o]) * scale[o] + bias[o]
// M = B*S = 8192, N = OUT = 11008, K = IN = 4096.
// Strategy: G = x @ W8^T via bf16 MFMA with split-precision x (hi+lo),
//           y = scale*G - scale*zero*rowsum(x) + bias.
// R2: T2 LDS XOR-swizzle (slot ^= row&7), applied as inverse-swizzled global
//     source (global_load_lds writes linearly) + swizzled ds_read address.

#define M_DIM 8192
#define N_DIM 11008
#define K_DIM 4096

typedef __attribute__((ext_vector_type(8))) __bf16 bf16x8;
typedef __attribute__((ext_vector_type(4))) float f32x4;

__device__ __forceinline__ unsigned short f32_to_bf16_rne(float f) {
  union { float f; uint32_t u; } v; v.f = f;
  uint32_t u = v.u;
  uint32_t r = (u + 0x7fffu + ((u >> 16) & 1u)) >> 16;
  return (unsigned short)r;
}
__device__ __forceinline__ float bf16_to_f32(unsigned short h) {
  union { uint32_t u; float f; } v; v.u = ((uint32_t)h) << 16; return v.f;
}

// ---------------- prep kernels ----------------

__global__ void convert_w_kernel(const int* __restrict__ w,
                                 unsigned short* __restrict__ out, int n4) {
  int idx = blockIdx.x * blockDim.x + threadIdx.x;
  int stride = gridDim.x * blockDim.x;
  for (int i = idx; i < n4; i += stride) {
    int4 v = ((const int4*)w)[i];
    ushort4 o;
    o.x = f32_to_bf16_rne((float)v.x);
    o.y = f32_to_bf16_rne((float)v.y);
    o.z = f32_to_bf16_rne((float)v.z);
    o.w = f32_to_bf16_rne((float)v.w);
    ((ushort4*)out)[i] = o;
  }
}

__global__ void convert_x_kernel(const float* __restrict__ x,
                                 unsigned short* __restrict__ hi,
                                 unsigned short* __restrict__ lo, int n4) {
  int idx = blockIdx.x * blockDim.x + threadIdx.x;
  int stride = gridDim.x * blockDim.x;
  for (int i = idx; i < n4; i += stride) {
    float4 v = ((const float4*)x)[i];
    ushort4 h, l;
    h.x = f32_to_bf16_rne(v.x); l.x = f32_to_bf16_rne(v.x - bf16_to_f32(h.x));
    h.y = f32_to_bf16_rne(v.y); l.y = f32_to_bf16_rne(v.y - bf16_to_f32(h.y));
    h.z = f32_to_bf16_rne(v.z); l.z = f32_to_bf16_rne(v.z - bf16_to_f32(h.z));
    h.w = f32_to_bf16_rne(v.w); l.w = f32_to_bf16_rne(v.w - bf16_to_f32(h.w));
    ((ushort4*)hi)[i] = h;
    ((ushort4*)lo)[i] = l;
  }
}

__global__ void rowsum_kernel(const float* __restrict__ x, float* __restrict__ rs) {
  const int row = blockIdx.x * 4 + (threadIdx.x >> 6);
  const int lane = threadIdx.x & 63;
  const float4* p = (const float4*)(x + (size_t)row * K_DIM);
  float s = 0.f;
  #pragma unroll 4
  for (int i = lane; i < K_DIM / 4; i += 64) {
    float4 v = p[i];
    s += v.x + v.y + v.z + v.w;
  }
  #pragma unroll
  for (int off = 32; off > 0; off >>= 1) s += __shfl_down(s, off);
  if (lane == 0) rs[row] = s;
}

// ---------------- main GEMM (128x128 tile, BK=64, 4 waves, T2 swizzle) ----------------

__global__ __launch_bounds__(256) void qgemm_kernel(
    const unsigned short* __restrict__ Ahi, const unsigned short* __restrict__ Alo,
    const unsigned short* __restrict__ Bw, const float* __restrict__ rowsum,
    const float* __restrict__ scale, const float* __restrict__ zero,
    const float* __restrict__ bias, float* __restrict__ out) {
  __shared__ unsigned short lds[3 * 128 * 64];  // Ahi | Alo | B, each [128][64], 48 KB
  unsigned short* ldsAhi = lds;
  unsigned short* ldsAlo = lds + 128 * 64;
  unsigned short* ldsB   = lds + 2 * 128 * 64;

  const int tid = threadIdx.x;
  const int wave = tid >> 6;
  const int lane = tid & 63;

  // grouped block mapping: 8 m-tiles per group x all n-tiles -> L2/L3 reuse
  const int NUM_N = N_DIM / 128;         // 86
  const int GROUP_M = 8;
  const int per_group = GROUP_M * NUM_N; // 688
  const int bid = blockIdx.x;
  const int group = bid / per_group;
  const int rem = bid % per_group;
  const int bm = group * GROUP_M + (rem % GROUP_M);  // 0..63
  const int bn = rem / GROUP_M;                      // 0..85

  const int wr = wave >> 1;  // 0..1  (64-row half)
  const int wc = wave & 1;   // 0..1  (64-col half)

  f32x4 acc[4][4];
  #pragma unroll
  for (int i = 0; i < 4; ++i)
    #pragma unroll
    for (int j = 0; j < 4; ++j) acc[i][j] = (f32x4){0.f, 0.f, 0.f, 0.f};

  // staging: per issue t, 256 lanes x 16B cover 32 rows x 64 cols (bf16).
  // LDS dest is linear (HW: wave-uniform base + lane*16); the 16B slot each
  // lane OWNS is (tid&7) of row srow. To realize phys_slot = log_slot ^ (row&7)
  // we load global slot (tid&7) ^ (srow&7). Note (srow&7) == (tid>>3)&7.
  const int srow = tid >> 3;                              // 0..31 within slab
  const int scol = (((tid & 7) ^ ((tid >> 3) & 7)) << 3); // swizzled k-offset (elems)
  const size_t a_base = (size_t)(bm * 128) * K_DIM;
  const size_t b_base = (size_t)(bn * 128) * K_DIM;

  // fragment read addressing: logical col chunk = kk + (lane>>4)*8;
  // 16B slot = kk/8 + (lane>>4); phys slot = slot ^ (row&7), and every
  // fragment row has row&7 == (lane&7)&7 == fr&7 -> hoist per-lane constants.
  const int fr = lane & 15;
  const int g = lane >> 4;       // 0..3
  const int sw = fr & 7;
  const int sc0 = ((g ^ sw) << 3);        // swizzled col (elems) for kk=0
  const int sc1 = (((g + 4) ^ sw) << 3);  // swizzled col (elems) for kk=32

  for (int ks = 0; ks < K_DIM; ks += 64) {
    #pragma unroll
    for (int t = 0; t < 4; ++t) {
      const int r = t * 32 + srow;
      const unsigned short* ga = Ahi + a_base + (size_t)r * K_DIM + ks + scol;
      const unsigned short* gl = Alo + a_base + (size_t)r * K_DIM + ks + scol;
      const unsigned short* gb = Bw  + b_base + (size_t)r * K_DIM + ks + scol;
      unsigned short* la = ldsAhi + t * 2048 + wave * 512;
      unsigned short* ll = ldsAlo + t * 2048 + wave * 512;
      unsigned short* lb = ldsB   + t * 2048 + wave * 512;
      __builtin_amdgcn_global_load_lds((const __attribute__((address_space(1))) void*)ga,
                                       (__attribute__((address_space(3))) void*)la, 16, 0, 0);
      __builtin_amdgcn_global_load_lds((const __attribute__((address_space(1))) void*)gl,
                                       (__attribute__((address_space(3))) void*)ll, 16, 0, 0);
      __builtin_amdgcn_global_load_lds((const __attribute__((address_space(1))) void*)gb,
                                       (__attribute__((address_space(3))) void*)lb, 16, 0, 0);
    }
    __syncthreads();

    #pragma unroll
    for (int kk = 0; kk < 64; kk += 32) {
      const int sc = (kk == 0) ? sc0 : sc1;
      bf16x8 bfrag[4];
      #pragma unroll
      for (int ni = 0; ni < 4; ++ni) {
        const int row = wc * 64 + ni * 16 + fr;
        bfrag[ni] = *(const bf16x8*)(ldsB + row * 64 + sc);
      }
      #pragma unroll
      for (int mi = 0; mi < 4; ++mi) {
        const int row = wr * 64 + mi * 16 + fr;
        bf16x8 ah = *(const bf16x8*)(ldsAhi + row * 64 + sc);
        bf16x8 al = *(const bf16x8*)(ldsAlo + row * 64 + sc);
        #pragma unroll
        for (int ni = 0; ni < 4; ++ni) {
          acc[mi][ni] = __builtin_amdgcn_mfma_f32_16x16x32_bf16(ah, bfrag[ni], acc[mi][ni], 0, 0, 0);
          acc[mi][ni] = __builtin_amdgcn_mfma_f32_16x16x32_bf16(al, bfrag[ni], acc[mi][ni], 0, 0, 0);
        }
      }
    }
    __syncthreads();
  }

  // epilogue: y = scale*G - scale*zero*rowsum + bias
  const int row0 = bm * 128 + wr * 64;
  const int col0 = bn * 128 + wc * 64;
  float s_[4], sz_[4], b_[4];
  #pragma unroll
  for (int ni = 0; ni < 4; ++ni) {
    const int n = col0 + ni * 16 + fr;
    const float s = scale[n];
    s_[ni] = s;
    sz_[ni] = s * zero[n];
    b_[ni] = bias[n];
  }
  #pragma unroll
  for (int mi = 0; mi < 4; ++mi) {
    #pragma unroll
    for (int j = 0; j < 4; ++j) {
      const int m = row0 + mi * 16 + (lane >> 4) * 4 + j;
      const float rs = rowsum[m];
      float* po = out + (size_t)m * N_DIM + col0;
      #pragma unroll
      for (int ni = 0; ni < 4; ++ni) {
        po[ni * 16 + fr] = s_[ni] * acc[mi][ni][j] - sz_[ni] * rs + b_[ni];
      }
    }
  }
}

// ---------------- fallback (only if workspace too small) ----------------

__global__ void fallback_kernel(const float* __restrict__ x, const int* __restrict__ w,
                                const float* __restrict__ scale, const float* __restrict__ zero,
                                const float* __restrict__ bias, float* __restrict__ out) {
  const int n = blockIdx.x * 16 + (threadIdx.x & 15);
  const int m = blockIdx.y * 16 + (threadIdx.x >> 4);
  const float z = zero[n];
  const float* xr = x + (size_t)m * K_DIM;
  const int* wr = w + (size_t)n * K_DIM;
  float acc = 0.f;
  for (int k = 0; k < K_DIM; ++k) acc += xr[k] * ((float)wr[k] - z);
  out[(size_t)m * N_DIM + n] = scale[n] * acc + bias[n];
}

// ---------------- launch ----------------

extern "C" void kernel_launch(void* const* d_in, const int* in_sizes, int n_in,
                              void* d_out, int out_size, void* d_ws, size_t ws_size,
                              hipStream_t stream) {
  const float* x     = (const float*)d_in[0];
  const int*   w     = (const int*)d_in[1];
  const float* scale = (const float*)d_in[2];
  const float* zero  = (const float*)d_in[3];
  const float* bias  = (const float*)d_in[4];
  float* out = (float*)d_out;

  const size_t n_x = (size_t)M_DIM * K_DIM;  // 33,554,432
  const size_t n_w = (size_t)N_DIM * K_DIM;  // 45,088,768
  const size_t need = n_x * 2 * 2 + n_w * 2 + (size_t)M_DIM * 4;  // ~214 MB

  if (ws_size < need) {
    dim3 g(N_DIM / 16, M_DIM / 16);
    fallback_kernel<<<g, 256, 0, stream>>>(x, w, scale, zero, bias, out);
    return;
  }

  unsigned short* x_hi = (unsigned short*)d_ws;
  unsigned short* x_lo = x_hi + n_x;
  unsigned short* w_bf = x_lo + n_x;
  float* rsum = (float*)(w_bf + n_w);

  convert_w_kernel<<<2048, 256, 0, stream>>>(w, w_bf, (int)(n_w / 4));
  convert_x_kernel<<<2048, 256, 0, stream>>>(x, x_hi, x_lo, (int)(n_x / 4));
  rowsum_kernel<<<M_DIM / 4, 256, 0, stream>>>(x, rsum);

  const int nblocks = (M_DIM / 128) * (N_DIM / 128);  // 64 * 86 = 5504
  qgemm_kernel<<<nblocks, 256, 0, stream>>>(x_hi, x_lo, w_bf, rsum,
                                            scale, zero, bias, out);
}

// Round 3
// 1269.263 us; speedup vs baseline: 1.2941x; 1.1988x over previous
//
#include <hip/hip_runtime.h>
#include <stdint.h>

// Problem: y[b,s,o] = sum_i x[b,s,i] * (W8[o,i] - zero[o]) * scale[o] + bias[o]
// M = B*S = 8192, N = OUT = 11008, K = IN = 4096.
// R3 strategy: per-row 15-bit fixed-point x: x ~= xs_m * (128*h + l), h,l int8.
//   G = x @ W8^T = xs_m * (128*(h@W8^T) + (l@W8^T)) via two i8 MFMA GEMMs.
//   y = scale*G - scale*zero*rowsum(x) + bias.
// LDS: [128][128] int8 tiles (128 B rows, 8 x 16B slots), XOR swizzle slot^=(row&7)
// realized as inverse-swizzled global source (global_load_lds writes linearly).

#define M_DIM 8192
#define N_DIM 11008
#define K_DIM 4096

typedef __attribute__((ext_vector_type(4))) int i32x4;

// ---------------- prep kernels ----------------

// W int32 (int8-valued) -> packed int8
__global__ void convert_w_kernel(const int* __restrict__ w,
                                 int8_t* __restrict__ o, int n4) {
  int idx = blockIdx.x * blockDim.x + threadIdx.x;
  int stride = gridDim.x * blockDim.x;
  for (int i = idx; i < n4; i += stride) {
    int4 v = ((const int4*)w)[i];
    int r = (v.x & 255) | ((v.y & 255) << 8) | ((v.z & 255) << 16) | ((v.w & 255) << 24);
    ((int*)o)[i] = r;
  }
}

// per-row: rowmax, rowsum, quantize x -> h,l int8 (15-bit fixed point)
__global__ __launch_bounds__(256) void quantx_kernel(
    const float* __restrict__ x, int8_t* __restrict__ h8, int8_t* __restrict__ l8,
    float* __restrict__ xs, float* __restrict__ rsum) {
  const int row = blockIdx.x;
  const int t = threadIdx.x;
  const float4* px = (const float4*)(x + (size_t)row * K_DIM);
  float4 v[4];
  float mx = 0.f, sm = 0.f;
  #pragma unroll
  for (int i = 0; i < 4; ++i) {
    v[i] = px[i * 256 + t];
    mx = fmaxf(mx, fmaxf(fmaxf(fabsf(v[i].x), fabsf(v[i].y)),
                         fmaxf(fabsf(v[i].z), fabsf(v[i].w))));
    sm += v[i].x + v[i].y + v[i].z + v[i].w;
  }
  #pragma unroll
  for (int off = 32; off > 0; off >>= 1) {
    mx = fmaxf(mx, __shfl_down(mx, off));
    sm += __shfl_down(sm, off);
  }
  __shared__ float rmx[4], rsm[4];
  const int wv = t >> 6, ln = t & 63;
  if (ln == 0) { rmx[wv] = mx; rsm[wv] = sm; }
  __syncthreads();
  const float rowmax = fmaxf(fmaxf(rmx[0], rmx[1]), fmaxf(rmx[2], rmx[3]));
  if (t == 0) {
    xs[row] = rowmax > 0.f ? rowmax / 16256.f : 0.f;
    rsum[row] = rsm[0] + rsm[1] + rsm[2] + rsm[3];
  }
  const float inv = rowmax > 0.f ? 16256.f / rowmax : 0.f;
  int* hp = (int*)(h8 + (size_t)row * K_DIM);
  int* lp = (int*)(l8 + (size_t)row * K_DIM);
  #pragma unroll
  for (int i = 0; i < 4; ++i) {
    int q0 = (int)rintf(v[i].x * inv);
    int q1 = (int)rintf(v[i].y * inv);
    int q2 = (int)rintf(v[i].z * inv);
    int q3 = (int)rintf(v[i].w * inv);
    int h0 = (q0 + 64) >> 7, h1 = (q1 + 64) >> 7, h2 = (q2 + 64) >> 7, h3 = (q3 + 64) >> 7;
    int l0 = q0 - (h0 << 7), l1 = q1 - (h1 << 7), l2 = q2 - (h2 << 7), l3 = q3 - (h3 << 7);
    hp[i * 256 + t] = (h0 & 255) | ((h1 & 255) << 8) | ((h2 & 255) << 16) | ((h3 & 255) << 24);
    lp[i * 256 + t] = (l0 & 255) | ((l1 & 255) << 8) | ((l2 & 255) << 16) | ((l3 & 255) << 24);
  }
}

// ---------------- main GEMM (128x128 tile, BK=128, 4 waves, i8 MFMA) ----------------

__global__ __launch_bounds__(256) void qgemm_kernel(
    const int8_t* __restrict__ Ah, const int8_t* __restrict__ Al,
    const int8_t* __restrict__ Bw, const float* __restrict__ xs,
    const float* __restrict__ rowsum, const float* __restrict__ scale,
    const float* __restrict__ zero, const float* __restrict__ bias,
    float* __restrict__ out) {
  __shared__ int8_t lds[3 * 128 * 128];  // Ah | Al | B, each [128][128] i8, 48 KB
  int8_t* ldsAh = lds;
  int8_t* ldsAl = lds + 16384;
  int8_t* ldsB  = lds + 32768;

  const int tid = threadIdx.x;
  const int wave = tid >> 6;
  const int lane = tid & 63;

  // grouped block mapping for L2/L3 reuse
  const int NUM_N = N_DIM / 128;         // 86
  const int GROUP_M = 8;
  const int per_group = GROUP_M * NUM_N; // 688
  const int bid = blockIdx.x;
  const int group = bid / per_group;
  const int rem = bid % per_group;
  const int bm = group * GROUP_M + (rem % GROUP_M);  // 0..63
  const int bn = rem / GROUP_M;                      // 0..85

  const int wr = wave >> 1;  // 64-row half
  const int wc = wave & 1;   // 64-col half

  i32x4 acch[4][4], accl[4][4];
  #pragma unroll
  for (int i = 0; i < 4; ++i)
    #pragma unroll
    for (int j = 0; j < 4; ++j) {
      acch[i][j] = (i32x4){0, 0, 0, 0};
      accl[i][j] = (i32x4){0, 0, 0, 0};
    }

  // staging: per issue t, 256 lanes x 16B = 32 rows x 128 B. Lane owns phys
  // slot (tid&7) of row (tid>>3); load global slot (tid&7)^((tid>>3)&7) so
  // that phys_slot = log_slot ^ (row&7).
  const int srow = tid >> 3;
  const int scol = (((tid & 7) ^ ((tid >> 3) & 7)) << 4);  // byte offset in row
  const size_t a_base = (size_t)(bm * 128) * K_DIM;
  const size_t b_base = (size_t)(bn * 128) * K_DIM;

  // fragment reads: logical slot = kk/16 + g (g = lane>>4); every fragment
  // row has row&7 == fr&7 -> phys col hoisted per-lane.
  const int fr = lane & 15;
  const int g = lane >> 4;
  const int sw = fr & 7;
  const int sc0 = ((g ^ sw) << 4);        // byte col for kk=0
  const int sc1 = (((g + 4) ^ sw) << 4);  // byte col for kk=64

  for (int ks = 0; ks < K_DIM; ks += 128) {
    #pragma unroll
    for (int t = 0; t < 4; ++t) {
      const int r = t * 32 + srow;
      const int8_t* ga = Ah + a_base + (size_t)r * K_DIM + ks + scol;
      const int8_t* gl = Al + a_base + (size_t)r * K_DIM + ks + scol;
      const int8_t* gb = Bw + b_base + (size_t)r * K_DIM + ks + scol;
      int8_t* la = ldsAh + t * 4096 + wave * 1024;
      int8_t* ll = ldsAl + t * 4096 + wave * 1024;
      int8_t* lb = ldsB  + t * 4096 + wave * 1024;
      __builtin_amdgcn_global_load_lds((const __attribute__((address_space(1))) void*)ga,
                                       (__attribute__((address_space(3))) void*)la, 16, 0, 0);
      __builtin_amdgcn_global_load_lds((const __attribute__((address_space(1))) void*)gl,
                                       (__attribute__((address_space(3))) void*)ll, 16, 0, 0);
      __builtin_amdgcn_global_load_lds((const __attribute__((address_space(1))) void*)gb,
                                       (__attribute__((address_space(3))) void*)lb, 16, 0, 0);
    }
    __syncthreads();

    #pragma unroll
    for (int kk = 0; kk < 128; kk += 64) {
      const int sc = (kk == 0) ? sc0 : sc1;
      i32x4 bfrag[4];
      #pragma unroll
      for (int ni = 0; ni < 4; ++ni) {
        const int row = wc * 64 + ni * 16 + fr;
        bfrag[ni] = *(const i32x4*)(ldsB + row * 128 + sc);
      }
      #pragma unroll
      for (int mi = 0; mi < 4; ++mi) {
        const int row = wr * 64 + mi * 16 + fr;
        i32x4 ah = *(const i32x4*)(ldsAh + row * 128 + sc);
        i32x4 al = *(const i32x4*)(ldsAl + row * 128 + sc);
        #pragma unroll
        for (int ni = 0; ni < 4; ++ni) {
          acch[mi][ni] = __builtin_amdgcn_mfma_i32_16x16x64_i8(ah, bfrag[ni], acch[mi][ni], 0, 0, 0);
          accl[mi][ni] = __builtin_amdgcn_mfma_i32_16x16x64_i8(al, bfrag[ni], accl[mi][ni], 0, 0, 0);
        }
      }
    }
    __syncthreads();
  }

  // epilogue: G = xs_m*(128*Gh + Gl); y = scale*G - scale*zero*rowsum + bias
  const int row0 = bm * 128 + wr * 64;
  const int col0 = bn * 128 + wc * 64;
  float s_[4], sz_[4], b_[4];
  #pragma unroll
  for (int ni = 0; ni < 4; ++ni) {
    const int n = col0 + ni * 16 + fr;
    const float s = scale[n];
    s_[ni] = s;
    sz_[ni] = s * zero[n];
    b_[ni] = bias[n];
  }
  #pragma unroll
  for (int mi = 0; mi < 4; ++mi) {
    #pragma unroll
    for (int j = 0; j < 4; ++j) {
      const int m = row0 + mi * 16 + g * 4 + j;
      const float xsm = xs[m];
      const float rs = rowsum[m];
      float* po = out + (size_t)m * N_DIM + col0;
      #pragma unroll
      for (int ni = 0; ni < 4; ++ni) {
        const float G = xsm * (128.f * (float)acch[mi][ni][j] + (float)accl[mi][ni][j]);
        po[ni * 16 + fr] = s_[ni] * G - sz_[ni] * rs + b_[ni];
      }
    }
  }
}

// ---------------- fallback (only if workspace too small) ----------------

__global__ void fallback_kernel(const float* __restrict__ x, const int* __restrict__ w,
                                const float* __restrict__ scale, const float* __restrict__ zero,
                                const float* __restrict__ bias, float* __restrict__ out) {
  const int n = blockIdx.x * 16 + (threadIdx.x & 15);
  const int m = blockIdx.y * 16 + (threadIdx.x >> 4);
  const float z = zero[n];
  const float* xr = x + (size_t)m * K_DIM;
  const int* wr = w + (size_t)n * K_DIM;
  float acc = 0.f;
  for (int k = 0; k < K_DIM; ++k) acc += xr[k] * ((float)wr[k] - z);
  out[(size_t)m * N_DIM + n] = scale[n] * acc + bias[n];
}

// ---------------- launch ----------------

extern "C" void kernel_launch(void* const* d_in, const int* in_sizes, int n_in,
                              void* d_out, int out_size, void* d_ws, size_t ws_size,
                              hipStream_t stream) {
  const float* x     = (const float*)d_in[0];
  const int*   w     = (const int*)d_in[1];
  const float* scale = (const float*)d_in[2];
  const float* zero  = (const float*)d_in[3];
  const float* bias  = (const float*)d_in[4];
  float* out = (float*)d_out;

  const size_t n_x = (size_t)M_DIM * K_DIM;  // 33,554,432
  const size_t n_w = (size_t)N_DIM * K_DIM;  // 45,088,768
  const size_t need = n_x * 2 + n_w + (size_t)M_DIM * 8;  // ~112 MB

  if (ws_size < need) {
    dim3 gr(N_DIM / 16, M_DIM / 16);
    fallback_kernel<<<gr, 256, 0, stream>>>(x, w, scale, zero, bias, out);
    return;
  }

  int8_t* x_h = (int8_t*)d_ws;
  int8_t* x_l = x_h + n_x;
  int8_t* w_8 = x_l + n_x;
  float* rsum = (float*)(w_8 + n_w);
  float* xs   = rsum + M_DIM;

  convert_w_kernel<<<2048, 256, 0, stream>>>(w, w_8, (int)(n_w / 4));
  quantx_kernel<<<M_DIM, 256, 0, stream>>>(x, x_h, x_l, xs, rsum);

  const int nblocks = (M_DIM / 128) * (N_DIM / 128);  // 64 * 86 = 5504
  qgemm_kernel<<<nblocks, 256, 0, stream>>>(x_h, x_l, w_8, xs, rsum,
                                            scale, zero, bias, out);
}

// Round 4
// 738.002 us; speedup vs baseline: 2.2257x; 1.7199x over previous
//
#include <hip/hip_runtime.h>
#include <stdint.h>

// y[m,o] = sum_k x[m,k]*(W8[o,k]-zero[o])*scale[o] + bias[o], M=8192 N=11008 K=4096.
// x ~= xs_m*(128*h + l) (h,l int8, 15-bit fixed point); G = xs_m*(128*Gh + Gl) via
// two i8 MFMA GEMMs sharing B-frags; y = scale*G - scale*zero*rowsum + bias.
// R4: 128x256 tile, BK=128, 8 waves, 128KB LDS double-buffer, prefetch-next +
// counted s_waitcnt vmcnt(8) + raw s_barrier (no __syncthreads drain in loop).
// T2 XOR swizzle (slot ^= row&7) via inverse-swizzled global source.

#define M_DIM 8192
#define N_DIM 11008
#define K_DIM 4096
#define NT    (K_DIM / 128)   // 32 K-tiles
#define BUFB  65536           // bytes per LDS buffer: Ah 16K | Al 16K | B 32K

typedef __attribute__((ext_vector_type(4))) int i32x4;

// ---------------- prep kernels ----------------

__global__ void convert_w_kernel(const int* __restrict__ w,
                                 int8_t* __restrict__ o, int n4) {
  int idx = blockIdx.x * blockDim.x + threadIdx.x;
  int stride = gridDim.x * blockDim.x;
  for (int i = idx; i < n4; i += stride) {
    int4 v = ((const int4*)w)[i];
    int r = (v.x & 255) | ((v.y & 255) << 8) | ((v.z & 255) << 16) | ((v.w & 255) << 24);
    ((int*)o)[i] = r;
  }
}

__global__ __launch_bounds__(256) void quantx_kernel(
    const float* __restrict__ x, int8_t* __restrict__ h8, int8_t* __restrict__ l8,
    float* __restrict__ xs, float* __restrict__ rsum) {
  const int row = blockIdx.x;
  const int t = threadIdx.x;
  const float4* px = (const float4*)(x + (size_t)row * K_DIM);
  float4 v[4];
  float mx = 0.f, sm = 0.f;
  #pragma unroll
  for (int i = 0; i < 4; ++i) {
    v[i] = px[i * 256 + t];
    mx = fmaxf(mx, fmaxf(fmaxf(fabsf(v[i].x), fabsf(v[i].y)),
                         fmaxf(fabsf(v[i].z), fabsf(v[i].w))));
    sm += v[i].x + v[i].y + v[i].z + v[i].w;
  }
  #pragma unroll
  for (int off = 32; off > 0; off >>= 1) {
    mx = fmaxf(mx, __shfl_down(mx, off));
    sm += __shfl_down(sm, off);
  }
  __shared__ float rmx[4], rsm[4];
  const int wv = t >> 6, ln = t & 63;
  if (ln == 0) { rmx[wv] = mx; rsm[wv] = sm; }
  __syncthreads();
  const float rowmax = fmaxf(fmaxf(rmx[0], rmx[1]), fmaxf(rmx[2], rmx[3]));
  if (t == 0) {
    xs[row] = rowmax > 0.f ? rowmax / 16256.f : 0.f;
    rsum[row] = rsm[0] + rsm[1] + rsm[2] + rsm[3];
  }
  const float inv = rowmax > 0.f ? 16256.f / rowmax : 0.f;
  int* hp = (int*)(h8 + (size_t)row * K_DIM);
  int* lp = (int*)(l8 + (size_t)row * K_DIM);
  #pragma unroll
  for (int i = 0; i < 4; ++i) {
    int q0 = (int)rintf(v[i].x * inv);
    int q1 = (int)rintf(v[i].y * inv);
    int q2 = (int)rintf(v[i].z * inv);
    int q3 = (int)rintf(v[i].w * inv);
    int h0 = (q0 + 64) >> 7, h1 = (q1 + 64) >> 7, h2 = (q2 + 64) >> 7, h3 = (q3 + 64) >> 7;
    int l0 = q0 - (h0 << 7), l1 = q1 - (h1 << 7), l2 = q2 - (h2 << 7), l3 = q3 - (h3 << 7);
    hp[i * 256 + t] = (h0 & 255) | ((h1 & 255) << 8) | ((h2 & 255) << 16) | ((h3 & 255) << 24);
    lp[i * 256 + t] = (l0 & 255) | ((l1 & 255) << 8) | ((l2 & 255) << 16) | ((l3 & 255) << 24);
  }
}

// ---------------- main GEMM ----------------

__device__ __forceinline__ void stage_tile(
    const int8_t* __restrict__ Ah, const int8_t* __restrict__ Al,
    const int8_t* __restrict__ Bw, size_t a_base, size_t b_base,
    int ks, int srow, int scol, int wave, int8_t* buf) {
  // 8 global_load_lds x 512 thr x 16B: Ah[128][128], Al[128][128], B[256][128]
  #pragma unroll
  for (int r = 0; r < 2; ++r) {
    const int8_t* g = Ah + a_base + (size_t)(r * 64 + srow) * K_DIM + ks + scol;
    __builtin_amdgcn_global_load_lds((const __attribute__((address_space(1))) void*)g,
        (__attribute__((address_space(3))) void*)(buf + r * 8192 + wave * 1024), 16, 0, 0);
  }
  #pragma unroll
  for (int r = 0; r < 2; ++r) {
    const int8_t* g = Al + a_base + (size_t)(r * 64 + srow) * K_DIM + ks + scol;
    __builtin_amdgcn_global_load_lds((const __attribute__((address_space(1))) void*)g,
        (__attribute__((address_space(3))) void*)(buf + 16384 + r * 8192 + wave * 1024), 16, 0, 0);
  }
  #pragma unroll
  for (int r = 0; r < 4; ++r) {
    const int8_t* g = Bw + b_base + (size_t)(r * 64 + srow) * K_DIM + ks + scol;
    __builtin_amdgcn_global_load_lds((const __attribute__((address_space(1))) void*)g,
        (__attribute__((address_space(3))) void*)(buf + 32768 + r * 8192 + wave * 1024), 16, 0, 0);
  }
}

__global__ __launch_bounds__(512, 2) void qgemm_kernel(
    const int8_t* __restrict__ Ah, const int8_t* __restrict__ Al,
    const int8_t* __restrict__ Bw, const float* __restrict__ xs,
    const float* __restrict__ rowsum, const float* __restrict__ scale,
    const float* __restrict__ zero, const float* __restrict__ bias,
    float* __restrict__ out) {
  extern __shared__ int8_t smem[];  // 2 x 64KB

  const int tid = threadIdx.x;
  const int wave = tid >> 6;
  const int lane = tid & 63;

  // XCD-chunked + grouped mapping: nwg=2752=8*344; each XCD gets an 8-bm strip.
  const int bid = blockIdx.x;
  const int wg = (bid & 7) * 344 + (bid >> 3);
  const int group = wg / 344;
  const int rem = wg % 344;
  const int bm = group * 8 + (rem & 7);  // 0..63 (M/128)
  const int bn = rem >> 3;               // 0..42 (N/256)

  const int wr = wave >> 2;  // 0..1: 64-row half of 128
  const int wc = wave & 3;   // 0..3: 64-col quarter of 256

  i32x4 acch[4][4], accl[4][4];
  #pragma unroll
  for (int i = 0; i < 4; ++i)
    #pragma unroll
    for (int j = 0; j < 4; ++j) {
      acch[i][j] = (i32x4){0, 0, 0, 0};
      accl[i][j] = (i32x4){0, 0, 0, 0};
    }

  // staging addressing: thread owns phys slot (tid&7) of row (tid>>3) in each
  // 64-row slab; load global slot (tid&7)^(row&7) so phys = logical ^ (row&7).
  const int srow = tid >> 3;                               // 0..63
  const int scol = (((tid & 7) ^ ((tid >> 3) & 7)) << 4);  // byte offset in 128B row
  const size_t a_base = (size_t)(bm * 128) * K_DIM;
  const size_t b_base = (size_t)((size_t)bn * 256) * K_DIM;

  // fragment reads: logical slot = g (+4 for kk=64); row&7 == fr&7 for all frags.
  const int fr = lane & 15;
  const int g = lane >> 4;
  const int sw = fr & 7;
  const int sc0 = ((g ^ sw) << 4);
  const int sc1 = (((g + 4) ^ sw) << 4);

  // prologue: stage tile 0, drain, barrier
  stage_tile(Ah, Al, Bw, a_base, b_base, 0, srow, scol, wave, smem);
  asm volatile("s_waitcnt vmcnt(0)" ::: "memory");
  asm volatile("s_barrier" ::: "memory");

  for (int t = 0; t < NT; ++t) {
    if (t + 1 < NT) {
      // prefetch next tile into the other buffer (read-safe: all waves passed
      // the previous end-barrier, done reading it)
      stage_tile(Ah, Al, Bw, a_base, b_base, (t + 1) * 128, srow, scol, wave,
                 smem + ((t + 1) & 1) * BUFB);
      // counted wait: the 8 newest (t+1) stay in flight; tile t's 8 are done
      asm volatile("s_waitcnt vmcnt(8)" ::: "memory");
    } else {
      asm volatile("s_waitcnt vmcnt(0)" ::: "memory");
    }
    asm volatile("s_barrier" ::: "memory");

    const int8_t* buf = smem + (t & 1) * BUFB;
    const int8_t* ldsAh_ = buf;
    const int8_t* ldsAl_ = buf + 16384;
    const int8_t* ldsB_  = buf + 32768;

    #pragma unroll
    for (int h = 0; h < 2; ++h) {
      const int sc = h ? sc1 : sc0;
      i32x4 bfrag[4];
      #pragma unroll
      for (int ni = 0; ni < 4; ++ni) {
        const int row = wc * 64 + ni * 16 + fr;
        bfrag[ni] = *(const i32x4*)(ldsB_ + row * 128 + sc);
      }
      #pragma unroll
      for (int mi = 0; mi < 4; ++mi) {
        const int arow = (wr * 64 + mi * 16 + fr) * 128 + sc;
        i32x4 ahf = *(const i32x4*)(ldsAh_ + arow);
        i32x4 alf = *(const i32x4*)(ldsAl_ + arow);
        #pragma unroll
        for (int ni = 0; ni < 4; ++ni) {
          acch[mi][ni] = __builtin_amdgcn_mfma_i32_16x16x64_i8(ahf, bfrag[ni], acch[mi][ni], 0, 0, 0);
          accl[mi][ni] = __builtin_amdgcn_mfma_i32_16x16x64_i8(alf, bfrag[ni], accl[mi][ni], 0, 0, 0);
        }
      }
    }
    asm volatile("s_barrier" ::: "memory");
  }

  // epilogue: G = xs_m*(128*Gh + Gl); y = scale*G - scale*zero*rowsum + bias
  const int row0 = bm * 128 + wr * 64;
  const int col0 = bn * 256 + wc * 64;
  float s_[4], sz_[4], b_[4];
  #pragma unroll
  for (int ni = 0; ni < 4; ++ni) {
    const int n = col0 + ni * 16 + fr;
    const float s = scale[n];
    s_[ni] = s;
    sz_[ni] = s * zero[n];
    b_[ni] = bias[n];
  }
  #pragma unroll
  for (int mi = 0; mi < 4; ++mi) {
    #pragma unroll
    for (int j = 0; j < 4; ++j) {
      const int m = row0 + mi * 16 + g * 4 + j;
      const float xsm = xs[m];
      const float rs = rowsum[m];
      float* po = out + (size_t)m * N_DIM + col0;
      #pragma unroll
      for (int ni = 0; ni < 4; ++ni) {
        const float G = xsm * (128.f * (float)acch[mi][ni][j] + (float)accl[mi][ni][j]);
        po[ni * 16 + fr] = s_[ni] * G - sz_[ni] * rs + b_[ni];
      }
    }
  }
}

// ---------------- fallback (only if workspace too small) ----------------

__global__ void fallback_kernel(const float* __restrict__ x, const int* __restrict__ w,
                                const float* __restrict__ scale, const float* __restrict__ zero,
                                const float* __restrict__ bias, float* __restrict__ out) {
  const int n = blockIdx.x * 16 + (threadIdx.x & 15);
  const int m = blockIdx.y * 16 + (threadIdx.x >> 4);
  const float z = zero[n];
  const float* xr = x + (size_t)m * K_DIM;
  const int* wr = w + (size_t)n * K_DIM;
  float acc = 0.f;
  for (int k = 0; k < K_DIM; ++k) acc += xr[k] * ((float)wr[k] - z);
  out[(size_t)m * N_DIM + n] = scale[n] * acc + bias[n];
}

// ---------------- launch ----------------

extern "C" void kernel_launch(void* const* d_in, const int* in_sizes, int n_in,
                              void* d_out, int out_size, void* d_ws, size_t ws_size,
                              hipStream_t stream) {
  const float* x     = (const float*)d_in[0];
  const int*   w     = (const int*)d_in[1];
  const float* scale = (const float*)d_in[2];
  const float* zero  = (const float*)d_in[3];
  const float* bias  = (const float*)d_in[4];
  float* out = (float*)d_out;

  const size_t n_x = (size_t)M_DIM * K_DIM;
  const size_t n_w = (size_t)N_DIM * K_DIM;
  const size_t need = n_x * 2 + n_w + (size_t)M_DIM * 8;  // ~112 MB

  if (ws_size < need) {
    dim3 gr(N_DIM / 16, M_DIM / 16);
    fallback_kernel<<<gr, 256, 0, stream>>>(x, w, scale, zero, bias, out);
    return;
  }

  int8_t* x_h = (int8_t*)d_ws;
  int8_t* x_l = x_h + n_x;
  int8_t* w_8 = x_l + n_x;
  float* rsum = (float*)(w_8 + n_w);
  float* xs   = rsum + M_DIM;

  convert_w_kernel<<<2048, 256, 0, stream>>>(w, w_8, (int)(n_w / 4));
  quantx_kernel<<<M_DIM, 256, 0, stream>>>(x, x_h, x_l, xs, rsum);

  // allow 128KB dynamic LDS (idempotent host-side call; not a stream op)
  (void)hipFuncSetAttribute((const void*)qgemm_kernel,
                            hipFuncAttributeMaxDynamicSharedMemorySize, 2 * BUFB);

  const int nblocks = (M_DIM / 128) * (N_DIM / 256);  // 64 * 43 = 2752
  qgemm_kernel<<<nblocks, 512, 2 * BUFB, stream>>>(x_h, x_l, w_8, xs, rsum,
                                                   scale, zero, bias, out);
}

// Round 5
// 736.536 us; speedup vs baseline: 2.2301x; 1.0020x over previous
//
#include <hip/hip_runtime.h>
#include <stdint.h>

// y[m,o] = sum_k x[m,k]*(W8[o,k]-zero[o])*scale[o] + bias[o], M=8192 N=11008 K=4096.
// x ~= xs_m*(128*h + l) (h,l int8); G = xs_m*(128*Gh + Gl) via two i8 MFMA GEMMs
// sharing B-frags; y = scale*G - scale*zero*rowsum + bias.
// R5: m201-style phased schedule: 4 phases per BK=128 tile, each
// {ds_read frag group || stage part of tile t+1 -> s_barrier -> lgkmcnt(0)+
//  sched_barrier -> setprio(1) -> 16 MFMA -> setprio(0) -> s_barrier}.
// Staging spread over phases 0-1; vmcnt(0) only at end of phase 3 (~800cy after
// last issue). T2 XOR swizzle (slot ^= row&7) via inverse-swizzled global src.

#define M_DIM 8192
#define N_DIM 11008
#define K_DIM 4096
#define NT    (K_DIM / 128)   // 32 K-tiles
#define BUFB  65536           // bytes per LDS buffer: Ah 16K | Al 16K | B 32K

typedef __attribute__((ext_vector_type(4))) int i32x4;

// ---------------- prep kernels ----------------

__global__ void convert_w_kernel(const int* __restrict__ w,
                                 int8_t* __restrict__ o, int n4) {
  int idx = blockIdx.x * blockDim.x + threadIdx.x;
  int stride = gridDim.x * blockDim.x;
  for (int i = idx; i < n4; i += stride) {
    int4 v = ((const int4*)w)[i];
    int r = (v.x & 255) | ((v.y & 255) << 8) | ((v.z & 255) << 16) | ((v.w & 255) << 24);
    ((int*)o)[i] = r;
  }
}

__global__ __launch_bounds__(256) void quantx_kernel(
    const float* __restrict__ x, int8_t* __restrict__ h8, int8_t* __restrict__ l8,
    float* __restrict__ xs, float* __restrict__ rsum) {
  const int row = blockIdx.x;
  const int t = threadIdx.x;
  const float4* px = (const float4*)(x + (size_t)row * K_DIM);
  float4 v[4];
  float mx = 0.f, sm = 0.f;
  #pragma unroll
  for (int i = 0; i < 4; ++i) {
    v[i] = px[i * 256 + t];
    mx = fmaxf(mx, fmaxf(fmaxf(fabsf(v[i].x), fabsf(v[i].y)),
                         fmaxf(fabsf(v[i].z), fabsf(v[i].w))));
    sm += v[i].x + v[i].y + v[i].z + v[i].w;
  }
  #pragma unroll
  for (int off = 32; off > 0; off >>= 1) {
    mx = fmaxf(mx, __shfl_down(mx, off));
    sm += __shfl_down(sm, off);
  }
  __shared__ float rmx[4], rsm[4];
  const int wv = t >> 6, ln = t & 63;
  if (ln == 0) { rmx[wv] = mx; rsm[wv] = sm; }
  __syncthreads();
  const float rowmax = fmaxf(fmaxf(rmx[0], rmx[1]), fmaxf(rmx[2], rmx[3]));
  if (t == 0) {
    xs[row] = rowmax > 0.f ? rowmax / 16256.f : 0.f;
    rsum[row] = rsm[0] + rsm[1] + rsm[2] + rsm[3];
  }
  const float inv = rowmax > 0.f ? 16256.f / rowmax : 0.f;
  int* hp = (int*)(h8 + (size_t)row * K_DIM);
  int* lp = (int*)(l8 + (size_t)row * K_DIM);
  #pragma unroll
  for (int i = 0; i < 4; ++i) {
    int q0 = (int)rintf(v[i].x * inv);
    int q1 = (int)rintf(v[i].y * inv);
    int q2 = (int)rintf(v[i].z * inv);
    int q3 = (int)rintf(v[i].w * inv);
    int h0 = (q0 + 64) >> 7, h1 = (q1 + 64) >> 7, h2 = (q2 + 64) >> 7, h3 = (q3 + 64) >> 7;
    int l0 = q0 - (h0 << 7), l1 = q1 - (h1 << 7), l2 = q2 - (h2 << 7), l3 = q3 - (h3 << 7);
    hp[i * 256 + t] = (h0 & 255) | ((h1 & 255) << 8) | ((h2 & 255) << 16) | ((h3 & 255) << 24);
    lp[i * 256 + t] = (l0 & 255) | ((l1 & 255) << 8) | ((l2 & 255) << 16) | ((l3 & 255) << 24);
  }
}

// ---------------- main GEMM ----------------

__device__ __forceinline__ void stage_A(
    const int8_t* __restrict__ Ah, const int8_t* __restrict__ Al,
    size_t a_base, int ks, int srow, int scol, int wave, int8_t* buf) {
  #pragma unroll
  for (int r = 0; r < 2; ++r) {
    const int8_t* g = Ah + a_base + (size_t)(r * 64 + srow) * K_DIM + ks + scol;
    __builtin_amdgcn_global_load_lds((const __attribute__((address_space(1))) void*)g,
        (__attribute__((address_space(3))) void*)(buf + r * 8192 + wave * 1024), 16, 0, 0);
  }
  #pragma unroll
  for (int r = 0; r < 2; ++r) {
    const int8_t* g = Al + a_base + (size_t)(r * 64 + srow) * K_DIM + ks + scol;
    __builtin_amdgcn_global_load_lds((const __attribute__((address_space(1))) void*)g,
        (__attribute__((address_space(3))) void*)(buf + 16384 + r * 8192 + wave * 1024), 16, 0, 0);
  }
}

__device__ __forceinline__ void stage_B(
    const int8_t* __restrict__ Bw, size_t b_base,
    int ks, int srow, int scol, int wave, int8_t* buf) {
  #pragma unroll
  for (int r = 0; r < 4; ++r) {
    const int8_t* g = Bw + b_base + (size_t)(r * 64 + srow) * K_DIM + ks + scol;
    __builtin_amdgcn_global_load_lds((const __attribute__((address_space(1))) void*)g,
        (__attribute__((address_space(3))) void*)(buf + 32768 + r * 8192 + wave * 1024), 16, 0, 0);
  }
}

#define WAIT_LGKM0() do { asm volatile("s_waitcnt lgkmcnt(0)" ::: "memory"); \
                          __builtin_amdgcn_sched_barrier(0); } while (0)

__global__ __launch_bounds__(512, 2) void qgemm_kernel(
    const int8_t* __restrict__ Ah, const int8_t* __restrict__ Al,
    const int8_t* __restrict__ Bw, const float* __restrict__ xs,
    const float* __restrict__ rowsum, const float* __restrict__ scale,
    const float* __restrict__ zero, const float* __restrict__ bias,
    float* __restrict__ out) {
  extern __shared__ int8_t smem[];  // 2 x 64KB

  const int tid = threadIdx.x;
  const int wave = tid >> 6;
  const int lane = tid & 63;

  // XCD-chunked + grouped mapping: nwg=2752=8*344; each XCD gets an 8-bm strip.
  const int bid = blockIdx.x;
  const int wg = (bid & 7) * 344 + (bid >> 3);
  const int group = wg / 344;
  const int rem = wg % 344;
  const int bm = group * 8 + (rem & 7);  // 0..63 (M/128)
  const int bn = rem >> 3;               // 0..42 (N/256)

  const int wr = wave >> 2;  // 0..1: 64-row half of 128
  const int wc = wave & 3;   // 0..3: 64-col quarter of 256

  i32x4 acch[4][4], accl[4][4];
  #pragma unroll
  for (int i = 0; i < 4; ++i)
    #pragma unroll
    for (int j = 0; j < 4; ++j) {
      acch[i][j] = (i32x4){0, 0, 0, 0};
      accl[i][j] = (i32x4){0, 0, 0, 0};
    }

  // staging addressing: thread owns phys slot (tid&7) of row (tid>>3); load
  // global slot (tid&7)^(row&7) so phys = logical ^ (row&7).
  const int srow = tid >> 3;                               // 0..63
  const int scol = (((tid & 7) ^ ((tid >> 3) & 7)) << 4);  // byte offset in 128B row
  const size_t a_base = (size_t)(bm * 128) * K_DIM;
  const size_t b_base = (size_t)((size_t)bn * 256) * K_DIM;

  // fragment reads: logical slot = g (+4 for kk=64); row&7 == fr&7 for all frags.
  const int fr = lane & 15;
  const int g = lane >> 4;
  const int sw = fr & 7;
  const int sc0 = ((g ^ sw) << 4);
  const int sc1 = (((g + 4) ^ sw) << 4);

  // prologue: stage tile 0, drain, barrier
  stage_A(Ah, Al, a_base, 0, srow, scol, wave, smem);
  stage_B(Bw, b_base, 0, srow, scol, wave, smem);
  asm volatile("s_waitcnt vmcnt(0)" ::: "memory");
  __builtin_amdgcn_s_barrier();

  for (int t = 0; t < NT; ++t) {
    const int8_t* buf = smem + (t & 1) * BUFB;
    int8_t* nxt = smem + ((t + 1) & 1) * BUFB;
    const int8_t* ldsAh_ = buf;
    const int8_t* ldsAl_ = buf + 16384;
    const int8_t* ldsB_  = buf + 32768;
    const bool pf = (t + 1 < NT);
    const int nks = (t + 1) * 128;

    i32x4 bfrag[4], af[2][2];

    // ---- phase 0: B(kk0) + A(mi0,1; kk0) reads || stage A(t+1) ----
    #pragma unroll
    for (int ni = 0; ni < 4; ++ni)
      bfrag[ni] = *(const i32x4*)(ldsB_ + (wc * 64 + ni * 16 + fr) * 128 + sc0);
    #pragma unroll
    for (int mi = 0; mi < 2; ++mi) {
      const int arow = (wr * 64 + mi * 16 + fr) * 128 + sc0;
      af[mi][0] = *(const i32x4*)(ldsAh_ + arow);
      af[mi][1] = *(const i32x4*)(ldsAl_ + arow);
    }
    if (pf) stage_A(Ah, Al, a_base, nks, srow, scol, wave, nxt);
    __builtin_amdgcn_s_barrier();
    WAIT_LGKM0();
    __builtin_amdgcn_s_setprio(1);
    #pragma unroll
    for (int mi = 0; mi < 2; ++mi)
      #pragma unroll
      for (int ni = 0; ni < 4; ++ni) {
        acch[mi][ni] = __builtin_amdgcn_mfma_i32_16x16x64_i8(af[mi][0], bfrag[ni], acch[mi][ni], 0, 0, 0);
        accl[mi][ni] = __builtin_amdgcn_mfma_i32_16x16x64_i8(af[mi][1], bfrag[ni], accl[mi][ni], 0, 0, 0);
      }
    __builtin_amdgcn_s_setprio(0);
    __builtin_amdgcn_s_barrier();

    // ---- phase 1: A(mi2,3; kk0) reads || stage B(t+1) ----
    #pragma unroll
    for (int mi = 0; mi < 2; ++mi) {
      const int arow = (wr * 64 + (mi + 2) * 16 + fr) * 128 + sc0;
      af[mi][0] = *(const i32x4*)(ldsAh_ + arow);
      af[mi][1] = *(const i32x4*)(ldsAl_ + arow);
    }
    if (pf) stage_B(Bw, b_base, nks, srow, scol, wave, nxt);
    __builtin_amdgcn_s_barrier();
    WAIT_LGKM0();
    __builtin_amdgcn_s_setprio(1);
    #pragma unroll
    for (int mi = 0; mi < 2; ++mi)
      #pragma unroll
      for (int ni = 0; ni < 4; ++ni) {
        acch[mi + 2][ni] = __builtin_amdgcn_mfma_i32_16x16x64_i8(af[mi][0], bfrag[ni], acch[mi + 2][ni], 0, 0, 0);
        accl[mi + 2][ni] = __builtin_amdgcn_mfma_i32_16x16x64_i8(af[mi][1], bfrag[ni], accl[mi + 2][ni], 0, 0, 0);
      }
    __builtin_amdgcn_s_setprio(0);
    __builtin_amdgcn_s_barrier();

    // ---- phase 2: B(kk1) + A(mi0,1; kk1) reads ----
    #pragma unroll
    for (int ni = 0; ni < 4; ++ni)
      bfrag[ni] = *(const i32x4*)(ldsB_ + (wc * 64 + ni * 16 + fr) * 128 + sc1);
    #pragma unroll
    for (int mi = 0; mi < 2; ++mi) {
      const int arow = (wr * 64 + mi * 16 + fr) * 128 + sc1;
      af[mi][0] = *(const i32x4*)(ldsAh_ + arow);
      af[mi][1] = *(const i32x4*)(ldsAl_ + arow);
    }
    __builtin_amdgcn_s_barrier();
    WAIT_LGKM0();
    __builtin_amdgcn_s_setprio(1);
    #pragma unroll
    for (int mi = 0; mi < 2; ++mi)
      #pragma unroll
      for (int ni = 0; ni < 4; ++ni) {
        acch[mi][ni] = __builtin_amdgcn_mfma_i32_16x16x64_i8(af[mi][0], bfrag[ni], acch[mi][ni], 0, 0, 0);
        accl[mi][ni] = __builtin_amdgcn_mfma_i32_16x16x64_i8(af[mi][1], bfrag[ni], accl[mi][ni], 0, 0, 0);
      }
    __builtin_amdgcn_s_setprio(0);
    __builtin_amdgcn_s_barrier();

    // ---- phase 3: A(mi2,3; kk1) reads; end-of-tile vmcnt ----
    #pragma unroll
    for (int mi = 0; mi < 2; ++mi) {
      const int arow = (wr * 64 + (mi + 2) * 16 + fr) * 128 + sc1;
      af[mi][0] = *(const i32x4*)(ldsAh_ + arow);
      af[mi][1] = *(const i32x4*)(ldsAl_ + arow);
    }
    __builtin_amdgcn_s_barrier();
    WAIT_LGKM0();
    __builtin_amdgcn_s_setprio(1);
    #pragma unroll
    for (int mi = 0; mi < 2; ++mi)
      #pragma unroll
      for (int ni = 0; ni < 4; ++ni) {
        acch[mi + 2][ni] = __builtin_amdgcn_mfma_i32_16x16x64_i8(af[mi][0], bfrag[ni], acch[mi + 2][ni], 0, 0, 0);
        accl[mi + 2][ni] = __builtin_amdgcn_mfma_i32_16x16x64_i8(af[mi][1], bfrag[ni], accl[mi + 2][ni], 0, 0, 0);
      }
    __builtin_amdgcn_s_setprio(0);
    // tile t+1's 8 loads were issued in phases 0-1 (~2 compute phases ago)
    asm volatile("s_waitcnt vmcnt(0)" ::: "memory");
    __builtin_amdgcn_s_barrier();
  }

  // epilogue: G = xs_m*(128*Gh + Gl); y = scale*G - scale*zero*rowsum + bias
  const int row0 = bm * 128 + wr * 64;
  const int col0 = bn * 256 + wc * 64;
  float s_[4], sz_[4], b_[4];
  #pragma unroll
  for (int ni = 0; ni < 4; ++ni) {
    const int n = col0 + ni * 16 + fr;
    const float s = scale[n];
    s_[ni] = s;
    sz_[ni] = s * zero[n];
    b_[ni] = bias[n];
  }
  #pragma unroll
  for (int mi = 0; mi < 4; ++mi) {
    #pragma unroll
    for (int j = 0; j < 4; ++j) {
      const int m = row0 + mi * 16 + g * 4 + j;
      const float xsm = xs[m];
      const float rs = rowsum[m];
      float* po = out + (size_t)m * N_DIM + col0;
      #pragma unroll
      for (int ni = 0; ni < 4; ++ni) {
        const float G = xsm * (128.f * (float)acch[mi][ni][j] + (float)accl[mi][ni][j]);
        po[ni * 16 + fr] = s_[ni] * G - sz_[ni] * rs + b_[ni];
      }
    }
  }
}

// ---------------- fallback (only if workspace too small) ----------------

__global__ void fallback_kernel(const float* __restrict__ x, const int* __restrict__ w,
                                const float* __restrict__ scale, const float* __restrict__ zero,
                                const float* __restrict__ bias, float* __restrict__ out) {
  const int n = blockIdx.x * 16 + (threadIdx.x & 15);
  const int m = blockIdx.y * 16 + (threadIdx.x >> 4);
  const float z = zero[n];
  const float* xr = x + (size_t)m * K_DIM;
  const int* wr = w + (size_t)n * K_DIM;
  float acc = 0.f;
  for (int k = 0; k < K_DIM; ++k) acc += xr[k] * ((float)wr[k] - z);
  out[(size_t)m * N_DIM + n] = scale[n] * acc + bias[n];
}

// ---------------- launch ----------------

extern "C" void kernel_launch(void* const* d_in, const int* in_sizes, int n_in,
                              void* d_out, int out_size, void* d_ws, size_t ws_size,
                              hipStream_t stream) {
  const float* x     = (const float*)d_in[0];
  const int*   w     = (const int*)d_in[1];
  const float* scale = (const float*)d_in[2];
  const float* zero  = (const float*)d_in[3];
  const float* bias  = (const float*)d_in[4];
  float* out = (float*)d_out;

  const size_t n_x = (size_t)M_DIM * K_DIM;
  const size_t n_w = (size_t)N_DIM * K_DIM;
  const size_t need = n_x * 2 + n_w + (size_t)M_DIM * 8;  // ~112 MB

  if (ws_size < need) {
    dim3 gr(N_DIM / 16, M_DIM / 16);
    fallback_kernel<<<gr, 256, 0, stream>>>(x, w, scale, zero, bias, out);
    return;
  }

  int8_t* x_h = (int8_t*)d_ws;
  int8_t* x_l = x_h + n_x;
  int8_t* w_8 = x_l + n_x;
  float* rsum = (float*)(w_8 + n_w);
  float* xs   = rsum + M_DIM;

  convert_w_kernel<<<2048, 256, 0, stream>>>(w, w_8, (int)(n_w / 4));
  quantx_kernel<<<M_DIM, 256, 0, stream>>>(x, x_h, x_l, xs, rsum);

  (void)hipFuncSetAttribute((const void*)qgemm_kernel,
                            hipFuncAttributeMaxDynamicSharedMemorySize, 2 * BUFB);

  const int nblocks = (M_DIM / 128) * (N_DIM / 256);  // 64 * 43 = 2752
  qgemm_kernel<<<nblocks, 512, 2 * BUFB, stream>>>(x_h, x_l, w_8, xs, rsum,
                                                   scale, zero, bias, out);
}